// Round 7
// baseline (200.913 us; speedup 1.0000x reference)
//
#include <hip/hip_runtime.h>
#include <stdint.h>

// VectorQuantize: x (8,256,32,32) f32, embed_w (4096,256) f32
// M = 8192 rows, K = 4096 codes, d = 256
// out (floats): [0,2097152) x_q (b,c,h,w); [2097152] loss; [2097153,2105345) embed_ind
//
// Round 7: 2 launches. R5 proved the gemm+out tail handoff correct (Path A passed)
// and isolated the 5.6x slowdown to per-block __threadfence() (agent release =>
// L2 writeback storm). Fences removed: cand/cnt are device-scope atomics
// (memory-side coherent); __syncthreads drains vmcnt(0) before the cnt add;
// tail reads cand via agent-scope atomic loads + one acquire on cnt.
//   K1 vq_prep: e-split + e2 + negx2 + zero cand/cnt/loss + x-split (race-free units)
//   K2 vq_gemm: R2/R6's 67us split-fp16 MFMA body + last-of-32-blocks out tail
// fp16 planes in ws (~12.5 MB, confirmed available by R5 Path A); fallback to
// 3-kernel R6 structure if ws is small.

typedef _Float16 f16;
typedef f16 half8 __attribute__((ext_vector_type(8)));
typedef float f32x4 __attribute__((ext_vector_type(4)));

__device__ __forceinline__ unsigned int sortable_f32(float v) {
    unsigned int u = __float_as_uint(v);
    return (u & 0x80000000u) ? ~u : (u | 0x80000000u);
}

__device__ __forceinline__ void gload_lds16(const void* g, void* l) {
    __builtin_amdgcn_global_load_lds(
        (const __attribute__((address_space(1))) unsigned int*)g,
        (__attribute__((address_space(3))) unsigned int*)l, 16, 0, 0);
}

// ================= K1: all prep, race-free unit partition (grid 1104) =================
__global__ void vq_prep(const float* __restrict__ x, const float* __restrict__ ew,
                        float* __restrict__ e2, float* __restrict__ negx2,
                        unsigned long long* __restrict__ cand, unsigned int* __restrict__ cnt,
                        f16* __restrict__ ehi, f16* __restrict__ elo,
                        f16* __restrict__ xhi, f16* __restrict__ xlo,
                        float* __restrict__ loss_cell) {
    __shared__ float xs[32][132];
    const int u = blockIdx.x, tid = threadIdx.x;
    if (u < 512) {
        // e-split (x 2^12, exact) into swizzled planes
        const int t = u * 256 + tid;            // 131072 = 4096 k * 32 groups
        const int k = t >> 5, g32 = t & 31;
        const float4 v0 = *(const float4*)(ew + k * 256 + g32 * 8);
        const float4 v1 = *(const float4*)(ew + k * 256 + g32 * 8 + 4);
        const float vf[8] = {v0.x, v0.y, v0.z, v0.w, v1.x, v1.y, v1.z, v1.w};
        half8 h1, h2;
#pragma unroll
        for (int j = 0; j < 8; ++j) {
            const float v = vf[j] * 4096.0f;    // exact (power of 2)
            const f16 a = (f16)v;
            const f16 b = (f16)(v - (float)a);  // exact in fp32
            h1[j] = a; h2[j] = b;
        }
        const int kt = k >> 7, kk = k & 127, ci = g32 >> 2, g = g32 & 3;
        const long off = ((long)((kt * 8 + ci) * 128 + kk)) * 32 + ((g ^ (kk & 3)) * 8);
        *(half8*)(ehi + off) = h1;
        *(half8*)(elo + off) = h2;
    } else if (u < 528) {
        // e2: bit-identical summation order to passing rounds
        const int k = (u - 512) * 256 + tid;
        const float4* row = (const float4*)(ew + k * 256);
        float s = 0.0f;
#pragma unroll 8
        for (int i = 0; i < 64; ++i) {
            float4 v = row[i];
            s += v.x * v.x + v.y * v.y + v.z * v.z + v.w * v.w;
        }
        e2[k] = s;
    } else if (u < 560) {
        const int z = (u - 528) * 256 + tid;    // 8192
        cand[z] = 0ull;
        if (z < 64) cnt[z] = 0u;
        if (z == 0) *loss_cell = 0.0f;
    } else if (u < 592) {
        // negx2 direct (R1 form, no atomics)
        const int r = (u - 560) * 256 + tid;    // 8192
        const int b = r >> 10, n = r & 1023;
        const float* px = x + b * 262144 + n;
        float s = 0.0f;
#pragma unroll 8
        for (int c = 0; c < 256; ++c) {
            float v = px[c << 10];
            s += v * v;
        }
        negx2[r] = -s;
    } else {
        // x-split: transpose (b,c,n)->(m,d) + fp16 split into swizzled planes
        const int unit = u - 592;               // 0..511
        const int ci = unit & 7, mt = unit >> 3;
        const int b = mt >> 3, n0 = (mt & 7) * 128, c0 = ci * 32;
#pragma unroll
        for (int it = 0; it < 4; ++it) {
            const int idx = tid + it * 256;
            const int cc = idx >> 5, nn4 = idx & 31;
            float4 v = *(const float4*)(x + b * 262144 + (c0 + cc) * 1024 + n0 + nn4 * 4);
            *(float4*)&xs[cc][nn4 * 4] = v;
        }
        __syncthreads();
#pragma unroll
        for (int it = 0; it < 2; ++it) {
            const int idx = tid + it * 256;
            const int mm = idx & 127, g = idx >> 7;
            half8 h1, h2;
#pragma unroll
            for (int j = 0; j < 8; ++j) {
                const float v = xs[g * 8 + j][mm];
                const f16 a = (f16)v;
                const f16 bb = (f16)(v - (float)a);
                h1[j] = a; h2[j] = bb;
            }
            const long off = ((long)((mt * 8 + ci) * 128 + mm)) * 32 + ((g ^ (mm & 3)) * 8);
            *(half8*)(xhi + off) = h1;
            *(half8*)(xlo + off) = h2;
        }
    }
}

// ================= K2: gemm (R2/R6 body) + fence-free last-block out tail =================
__launch_bounds__(256, 2)
__global__ void vq_gemm(const f16* __restrict__ xhi, const f16* __restrict__ xlo,
                        const f16* __restrict__ ehi, const f16* __restrict__ elo,
                        const float* __restrict__ e2, const float* __restrict__ negx2,
                        unsigned long long* __restrict__ cand, unsigned int* __restrict__ cnt,
                        const float* __restrict__ x, const float* __restrict__ ew,
                        float* __restrict__ out, int do_tail) {
    __shared__ __align__(16) f16 lds[16384];  // 32 KB: xhi|xlo|ehi|elo, 4096 halves each
    const int tid = threadIdx.x;
    const int kt = blockIdx.x, mt = blockIdx.y;
    const int lane = tid & 63, wave = tid >> 6;
    const int wm = wave >> 1, wk = wave & 1;
    const int col = lane & 15, quad = lane >> 4;

    f32x4 acc[4][4] = {};

    const f16* gx[2] = { xhi + (size_t)(mt * 8) * 4096, xlo + (size_t)(mt * 8) * 4096 };
    const f16* ge[2] = { ehi + (size_t)(kt * 8) * 4096, elo + (size_t)(kt * 8) * 4096 };

    int aoff[4], boff[4];
#pragma unroll
    for (int i = 0; i < 4; ++i) {
        const int m = wm * 64 + i * 16 + col;
        aoff[i] = m * 32 + ((quad ^ (m & 3)) * 8);
        const int k = wk * 64 + i * 16 + col;
        boff[i] = k * 32 + ((quad ^ (k & 3)) * 8);
    }

    for (int ci = 0; ci < 8; ++ci) {
        __syncthreads();
        const int go = ci * 4096 + tid * 8;             // halves
        char* lb = (char*)lds + wave * 1024;            // wave-uniform dst base
#pragma unroll
        for (int p = 0; p < 2; ++p) {
            gload_lds16(gx[p] + go,        lb + p * 8192);
            gload_lds16(gx[p] + go + 2048, lb + p * 8192 + 4096);
            gload_lds16(ge[p] + go,        lb + 16384 + p * 8192);
            gload_lds16(ge[p] + go + 2048, lb + 16384 + p * 8192 + 4096);
        }
        __syncthreads();

        half8 ahi4[4], alo4[4], bhi4[4], blo4[4];
#pragma unroll
        for (int i = 0; i < 4; ++i) {
            ahi4[i] = *(const half8*)&lds[aoff[i]];
            alo4[i] = *(const half8*)&lds[4096 + aoff[i]];
            bhi4[i] = *(const half8*)&lds[8192 + boff[i]];
            blo4[i] = *(const half8*)&lds[12288 + boff[i]];
        }
#pragma unroll
        for (int i = 0; i < 4; ++i)
#pragma unroll
            for (int j = 0; j < 4; ++j) {
                acc[i][j] = __builtin_amdgcn_mfma_f32_16x16x32_f16(ahi4[i], bhi4[j], acc[i][j], 0, 0, 0);
                acc[i][j] = __builtin_amdgcn_mfma_f32_16x16x32_f16(ahi4[i], blo4[j], acc[i][j], 0, 0, 0);
                acc[i][j] = __builtin_amdgcn_mfma_f32_16x16x32_f16(alo4[i], bhi4[j], acc[i][j], 0, 0, 0);
            }
    }

    // epilogue: C layout col=lane&15, row=quad*4+reg
    const int m0 = mt * 128 + wm * 64, k0 = kt * 128 + wk * 64;
#pragma unroll
    for (int i = 0; i < 4; ++i)
#pragma unroll
        for (int r = 0; r < 4; ++r) {
            const float A = negx2[m0 + i * 16 + quad * 4 + r];
            unsigned long long bk = 0ull;
#pragma unroll
            for (int j = 0; j < 4; ++j) {
                const int k = k0 + j * 16 + col;
                const float t1 = A - e2[k];                        // rounding 1
                const float dist = t1 + acc[i][j][r] * 0x1p-11f;   // exact scale; rounding 2
                const unsigned long long key =
                    ((unsigned long long)sortable_f32(dist) << 32)
                    | (unsigned long long)(unsigned int)(4095 - k);
                if (key > bk) bk = key;
            }
#pragma unroll
            for (int mask = 1; mask <= 8; mask <<= 1) {
                const unsigned long long o = __shfl_xor(bk, mask, 64);
                if (o > bk) bk = o;
            }
            if (col == i * 4 + r)
                atomicMax(&cand[m0 + i * 16 + quad * 4 + r], bk);
        }

    if (!do_tail) return;

    // ---- last-of-32 block for this mt runs the out phase for rows mt*128..+127.
    // NO __threadfence(): cand writes are device-scope atomics (memory-side
    // coherent); __syncthreads drains vmcnt(0) so they are complete before the
    // cnt add is issued. (R5 measured per-block threadfence = L2 wb storm, 5.6x.)
    __syncthreads();
    __shared__ unsigned int sOld;
    if (tid == 0) sOld = atomicAdd(&cnt[mt], 1u);
    __syncthreads();
    if (sOld != 31u) return;
    // one acquire per tail block (64 total): orders the cand reads below
    (void)__hip_atomic_load(&cnt[mt], __ATOMIC_ACQUIRE, __HIP_MEMORY_SCOPE_AGENT);

    const int r0 = mt * 128;
    const int b = r0 >> 10, n0 = r0 & 1023;
    int* sidx = (int*)lds;
    float* wsum = (float*)((char*)lds + 1024);
    if (tid < 128) {
        const int r = r0 + tid;
        const unsigned long long bk =
            __hip_atomic_load(&cand[r], __ATOMIC_RELAXED, __HIP_MEMORY_SCOPE_AGENT);
        const int idx = 4095 - (int)(unsigned int)(bk & 0xFFFFFFFFull);
        sidx[tid] = idx;
        out[2097153 + r] = (float)idx;
    }
    __syncthreads();
    const int nn = tid & 127, ch = tid >> 7;
    const int myidx = sidx[nn];
    float lsum = 0.0f;
#pragma unroll 4
    for (int cb = 0; cb < 128; ++cb) {
        const int c = ch * 128 + cb;
        const float ve = ew[myidx * 256 + c];
        const long off = (long)b * 262144 + (c << 10) + n0 + nn;
        const float vx = x[off];
        out[off] = ve;
        const float d = ve - vx;
        lsum += d * d;
    }
#pragma unroll
    for (int o = 32; o > 0; o >>= 1) lsum += __shfl_down(lsum, o, 64);
    if ((tid & 63) == 0) wsum[tid >> 6] = lsum;
    __syncthreads();
    if (tid == 0)
        atomicAdd(&out[2097152],
                  1.25f * ((wsum[0] + wsum[1] + wsum[2] + wsum[3]) / 2097152.0f));
}

// ================= fallback K3 (only if ws too small): R6's vq_out =================
__global__ void vq_out(const float* __restrict__ x, const float* __restrict__ ew,
                       const unsigned long long* __restrict__ cand,
                       float* __restrict__ out) {
    __shared__ int sidx[64];
    __shared__ float wsum[4];
    const int tid = threadIdx.x;
    const int r0 = blockIdx.x * 64;
    const int cq0 = blockIdx.y * 64;
    const int b = r0 >> 10, n0 = r0 & 1023;
    if (tid < 64) {
        const int r = r0 + tid;
        const unsigned long long bk = cand[r];
        const int idx = 4095 - (int)(unsigned int)(bk & 0xFFFFFFFFull);
        sidx[tid] = idx;
        if (cq0 == 0) out[2097153 + r] = (float)idx;
    }
    __syncthreads();
    const int nn = tid & 63, cq = tid >> 6;
    const int myidx = sidx[nn];
    float lsum = 0.0f;
#pragma unroll 4
    for (int cb = 0; cb < 16; ++cb) {
        const int c = cq0 + cb * 4 + cq;
        const float ve = ew[myidx * 256 + c];
        const long off = (long)b * 262144 + (c << 10) + n0 + nn;
        const float vx = x[off];
        out[off] = ve;
        const float d = ve - vx;
        lsum += d * d;
    }
#pragma unroll
    for (int o = 32; o > 0; o >>= 1) lsum += __shfl_down(lsum, o, 64);
    if ((tid & 63) == 0) wsum[tid >> 6] = lsum;
    __syncthreads();
    if (tid == 0)
        atomicAdd(&out[2097152],
                  1.25f * ((wsum[0] + wsum[1] + wsum[2] + wsum[3]) / 2097152.0f));
}

extern "C" void kernel_launch(void* const* d_in, const int* in_sizes, int n_in,
                              void* d_out, int out_size, void* d_ws, size_t ws_size,
                              hipStream_t stream) {
    const float* x  = (const float*)d_in[0];
    const float* ew = (const float*)d_in[1];
    float* out = (float*)d_out;

    float* e2 = (float*)d_ws;                                              // 16 KB
    float* negx2 = e2 + 4096;                                              // 32 KB
    unsigned long long* cand = (unsigned long long*)((char*)d_ws + 49152); // 64 KB
    unsigned int* cnt = (unsigned int*)((char*)d_ws + 114688);             // 256 B
    f16* ehi = (f16*)((char*)d_ws + 114944);                               // 2 MB
    f16* elo = (f16*)((char*)d_ws + 114944 + 2097152);                     // 2 MB

    const size_t need = 114944ull + 2ull * 2097152ull + 2ull * 4194304ull; // ~12.5 MB
    if (ws_size >= need) {
        // Path A: planes fully in ws; 2 kernels, out fused into gemm tail
        f16* xhi = (f16*)((char*)d_ws + 114944 + 2 * 2097152);             // 4 MB
        f16* xlo = (f16*)((char*)d_ws + 114944 + 2 * 2097152 + 4194304);   // 4 MB
        vq_prep<<<1104, 256, 0, stream>>>(x, ew, e2, negx2, cand, cnt,
                                          ehi, elo, xhi, xlo, out + 2097152);
        vq_gemm<<<dim3(32, 64), 256, 0, stream>>>(xhi, xlo, ehi, elo, e2, negx2,
                                                  cand, cnt, x, ew, out, 1);
    } else {
        // Path B: x-planes scratch in d_out's x_q region; 3 kernels (R6-proven)
        f16* xhi = (f16*)out;
        f16* xlo = (f16*)(out + 1048576);
        vq_prep<<<1104, 256, 0, stream>>>(x, ew, e2, negx2, cand, cnt,
                                          ehi, elo, xhi, xlo, out + 2097152);
        vq_gemm<<<dim3(32, 64), 256, 0, stream>>>(xhi, xlo, ehi, elo, e2, negx2,
                                                  cand, cnt, x, ew, out, 0);
        vq_out<<<dim3(128, 4), 256, 0, stream>>>(x, ew, cand, out);
    }
}

// Round 8
// 153.844 us; speedup vs baseline: 1.3060x; 1.3060x over previous
//
#include <hip/hip_runtime.h>
#include <stdint.h>

// VectorQuantize: x (8,256,32,32) f32, embed_w (4096,256) f32
// M = 8192 rows, K = 4096 codes, d = 256
// out (floats): [0,2097152) x_q (b,c,h,w); [2097152] loss; [2097153,2105345) embed_ind
//
// Round 8: R6 3-launch structure (proven 156us; tail-fusion abandoned after two
// differently-broken attempts). Gemm change only: e-fragments now load directly
// global->VGPR (e-planes are L2-resident; frag loads are fully coalesced via the
// baked-in XOR swizzle), LDS stages x-planes only. Halves LDS read+write traffic
// (the binding pipe at MfmaUtil 29%) and drops LDS/block to 16 KB.

typedef _Float16 f16;
typedef f16 half8 __attribute__((ext_vector_type(8)));
typedef float f32x4 __attribute__((ext_vector_type(4)));

__device__ __forceinline__ unsigned int sortable_f32(float v) {
    unsigned int u = __float_as_uint(v);
    return (u & 0x80000000u) ? ~u : (u | 0x80000000u);
}

__device__ __forceinline__ void gload_lds16(const void* g, void* l) {
    __builtin_amdgcn_global_load_lds(
        (const __attribute__((address_space(1))) unsigned int*)g,
        (__attribute__((address_space(3))) unsigned int*)l, 16, 0, 0);
}

// ================= K1: all prep, race-free unit partition (grid 1104) =================
__global__ void vq_prep(const float* __restrict__ x, const float* __restrict__ ew,
                        float* __restrict__ e2, float* __restrict__ negx2,
                        unsigned long long* __restrict__ cand,
                        f16* __restrict__ ehi, f16* __restrict__ elo,
                        f16* __restrict__ xhi, f16* __restrict__ xlo,
                        float* __restrict__ loss_cell) {
    __shared__ float xs[32][132];
    const int u = blockIdx.x, tid = threadIdx.x;
    if (u < 512) {
        // e-split (x 2^12, exact) into swizzled planes
        const int t = u * 256 + tid;            // 131072 = 4096 k * 32 groups
        const int k = t >> 5, g32 = t & 31;
        const float4 v0 = *(const float4*)(ew + k * 256 + g32 * 8);
        const float4 v1 = *(const float4*)(ew + k * 256 + g32 * 8 + 4);
        const float vf[8] = {v0.x, v0.y, v0.z, v0.w, v1.x, v1.y, v1.z, v1.w};
        half8 h1, h2;
#pragma unroll
        for (int j = 0; j < 8; ++j) {
            const float v = vf[j] * 4096.0f;    // exact (power of 2)
            const f16 a = (f16)v;
            const f16 b = (f16)(v - (float)a);  // exact in fp32
            h1[j] = a; h2[j] = b;
        }
        const int kt = k >> 7, kk = k & 127, ci = g32 >> 2, g = g32 & 3;
        const long off = ((long)((kt * 8 + ci) * 128 + kk)) * 32 + ((g ^ (kk & 3)) * 8);
        *(half8*)(ehi + off) = h1;
        *(half8*)(elo + off) = h2;
    } else if (u < 528) {
        // e2: bit-identical summation order to passing rounds
        const int k = (u - 512) * 256 + tid;
        const float4* row = (const float4*)(ew + k * 256);
        float s = 0.0f;
#pragma unroll 8
        for (int i = 0; i < 64; ++i) {
            float4 v = row[i];
            s += v.x * v.x + v.y * v.y + v.z * v.z + v.w * v.w;
        }
        e2[k] = s;
    } else if (u < 560) {
        const int z = (u - 528) * 256 + tid;    // 8192
        cand[z] = 0ull;
        if (z == 0) *loss_cell = 0.0f;
    } else if (u < 592) {
        // negx2 direct (R1 form, no atomics)
        const int r = (u - 560) * 256 + tid;    // 8192
        const int b = r >> 10, n = r & 1023;
        const float* px = x + b * 262144 + n;
        float s = 0.0f;
#pragma unroll 8
        for (int c = 0; c < 256; ++c) {
            float v = px[c << 10];
            s += v * v;
        }
        negx2[r] = -s;
    } else {
        // x-split: transpose (b,c,n)->(m,d) + fp16 split into swizzled planes
        const int unit = u - 592;               // 0..511
        const int ci = unit & 7, mt = unit >> 3;
        const int b = mt >> 3, n0 = (mt & 7) * 128, c0 = ci * 32;
#pragma unroll
        for (int it = 0; it < 4; ++it) {
            const int idx = tid + it * 256;
            const int cc = idx >> 5, nn4 = idx & 31;
            float4 v = *(const float4*)(x + b * 262144 + (c0 + cc) * 1024 + n0 + nn4 * 4);
            *(float4*)&xs[cc][nn4 * 4] = v;
        }
        __syncthreads();
#pragma unroll
        for (int it = 0; it < 2; ++it) {
            const int idx = tid + it * 256;
            const int mm = idx & 127, g = idx >> 7;
            half8 h1, h2;
#pragma unroll
            for (int j = 0; j < 8; ++j) {
                const float v = xs[g * 8 + j][mm];
                const f16 a = (f16)v;
                const f16 bb = (f16)(v - (float)a);
                h1[j] = a; h2[j] = bb;
            }
            const long off = ((long)((mt * 8 + ci) * 128 + mm)) * 32 + ((g ^ (mm & 3)) * 8);
            *(half8*)(xhi + off) = h1;
            *(half8*)(xlo + off) = h2;
        }
    }
}

// ================= K2: gemm — A via LDS DMA, B frags direct global->VGPR =================
__launch_bounds__(256, 2)
__global__ void vq_gemm(const f16* __restrict__ xhi, const f16* __restrict__ xlo,
                        const f16* __restrict__ ehi, const f16* __restrict__ elo,
                        const float* __restrict__ e2, const float* __restrict__ negx2,
                        unsigned long long* __restrict__ cand) {
    __shared__ __align__(16) f16 lds[8192];   // 16 KB: xhi | xlo, 4096 halves each
    const int tid = threadIdx.x;
    const int kt = blockIdx.x, mt = blockIdx.y;
    const int lane = tid & 63, wave = tid >> 6;
    const int wm = wave >> 1, wk = wave & 1;
    const int col = lane & 15, quad = lane >> 4;

    f32x4 acc[4][4] = {};

    const f16* gx[2] = { xhi + (size_t)(mt * 8) * 4096, xlo + (size_t)(mt * 8) * 4096 };
    const f16* geh = ehi + (size_t)(kt * 8) * 4096;
    const f16* gel = elo + (size_t)(kt * 8) * 4096;

    int aoff[4], boff[4];
#pragma unroll
    for (int i = 0; i < 4; ++i) {
        const int m = wm * 64 + i * 16 + col;
        aoff[i] = m * 32 + ((quad ^ (m & 3)) * 8);
        const int k = wk * 64 + i * 16 + col;
        boff[i] = k * 32 + ((quad ^ (k & 3)) * 8);   // same XOR layout baked into planes
    }

    for (int ci = 0; ci < 8; ++ci) {
        __syncthreads();
        const int go = ci * 4096 + tid * 8;             // halves
        char* lb = (char*)lds + wave * 1024;            // wave-uniform dst base
#pragma unroll
        for (int p = 0; p < 2; ++p) {
            gload_lds16(gx[p] + go,        lb + p * 8192);
            gload_lds16(gx[p] + go + 2048, lb + p * 8192 + 4096);
        }
        // B fragments: direct global loads (L2-resident e-planes, fully coalesced:
        // 64 lanes x 16B cover 16 whole cachelines per frag thanks to the XOR swizzle)
        half8 bhi4[4], blo4[4];
#pragma unroll
        for (int j = 0; j < 4; ++j) {
            bhi4[j] = *(const half8*)(geh + ci * 4096 + boff[j]);
            blo4[j] = *(const half8*)(gel + ci * 4096 + boff[j]);
        }
        __syncthreads();

        half8 ahi4[4], alo4[4];
#pragma unroll
        for (int i = 0; i < 4; ++i) {
            ahi4[i] = *(const half8*)&lds[aoff[i]];
            alo4[i] = *(const half8*)&lds[4096 + aoff[i]];
        }
#pragma unroll
        for (int i = 0; i < 4; ++i)
#pragma unroll
            for (int j = 0; j < 4; ++j) {
                acc[i][j] = __builtin_amdgcn_mfma_f32_16x16x32_f16(ahi4[i], bhi4[j], acc[i][j], 0, 0, 0);
                acc[i][j] = __builtin_amdgcn_mfma_f32_16x16x32_f16(ahi4[i], blo4[j], acc[i][j], 0, 0, 0);
                acc[i][j] = __builtin_amdgcn_mfma_f32_16x16x32_f16(alo4[i], bhi4[j], acc[i][j], 0, 0, 0);
            }
    }

    // epilogue: C layout col=lane&15, row=quad*4+reg
    const int m0 = mt * 128 + wm * 64, k0 = kt * 128 + wk * 64;
#pragma unroll
    for (int i = 0; i < 4; ++i)
#pragma unroll
        for (int r = 0; r < 4; ++r) {
            const float A = negx2[m0 + i * 16 + quad * 4 + r];
            unsigned long long bk = 0ull;
#pragma unroll
            for (int j = 0; j < 4; ++j) {
                const int k = k0 + j * 16 + col;
                const float t1 = A - e2[k];                        // rounding 1
                const float dist = t1 + acc[i][j][r] * 0x1p-11f;   // exact scale; rounding 2
                const unsigned long long key =
                    ((unsigned long long)sortable_f32(dist) << 32)
                    | (unsigned long long)(unsigned int)(4095 - k);
                if (key > bk) bk = key;
            }
#pragma unroll
            for (int mask = 1; mask <= 8; mask <<= 1) {
                const unsigned long long o = __shfl_xor(bk, mask, 64);
                if (o > bk) bk = o;
            }
            if (col == i * 4 + r)
                atomicMax(&cand[m0 + i * 16 + quad * 4 + r], bk);
        }
}

// ================= K3: gather, transposed store, loss, embed_ind =================
__global__ void vq_out(const float* __restrict__ x, const float* __restrict__ ew,
                       const unsigned long long* __restrict__ cand,
                       float* __restrict__ out) {
    __shared__ int sidx[64];
    __shared__ float wsum[4];
    const int tid = threadIdx.x;
    const int r0 = blockIdx.x * 64;
    const int cq0 = blockIdx.y * 64;
    const int b = r0 >> 10, n0 = r0 & 1023;
    if (tid < 64) {
        const int r = r0 + tid;
        const unsigned long long bk = cand[r];
        const int idx = 4095 - (int)(unsigned int)(bk & 0xFFFFFFFFull);
        sidx[tid] = idx;
        if (cq0 == 0) out[2097153 + r] = (float)idx;
    }
    __syncthreads();
    const int nn = tid & 63, cq = tid >> 6;
    const int myidx = sidx[nn];
    float lsum = 0.0f;
#pragma unroll 4
    for (int cb = 0; cb < 16; ++cb) {
        const int c = cq0 + cb * 4 + cq;
        const float ve = ew[myidx * 256 + c];
        const long off = (long)b * 262144 + (c << 10) + n0 + nn;
        const float vx = x[off];
        out[off] = ve;
        const float d = ve - vx;
        lsum += d * d;
    }
#pragma unroll
    for (int o = 32; o > 0; o >>= 1) lsum += __shfl_down(lsum, o, 64);
    if ((tid & 63) == 0) wsum[tid >> 6] = lsum;
    __syncthreads();
    if (tid == 0)
        atomicAdd(&out[2097152],
                  1.25f * ((wsum[0] + wsum[1] + wsum[2] + wsum[3]) / 2097152.0f));
}

extern "C" void kernel_launch(void* const* d_in, const int* in_sizes, int n_in,
                              void* d_out, int out_size, void* d_ws, size_t ws_size,
                              hipStream_t stream) {
    const float* x  = (const float*)d_in[0];
    const float* ew = (const float*)d_in[1];
    float* out = (float*)d_out;

    float* e2 = (float*)d_ws;                                              // 16 KB
    float* negx2 = e2 + 4096;                                              // 32 KB
    unsigned long long* cand = (unsigned long long*)((char*)d_ws + 49152); // 64 KB
    f16* ehi = (f16*)((char*)d_ws + 114688);                               // 2 MB (4K-aligned)
    f16* elo = (f16*)((char*)d_ws + 114688 + 2097152);                     // 2 MB
    f16* xhi = (f16*)out;                                                  // x_q region scratch
    f16* xlo = (f16*)(out + 1048576);

    vq_prep<<<1104, 256, 0, stream>>>(x, ew, e2, negx2, cand,
                                      ehi, elo, xhi, xlo, out + 2097152);
    vq_gemm<<<dim3(32, 64), 256, 0, stream>>>(xhi, xlo, ehi, elo, e2, negx2, cand);
    vq_out<<<dim3(128, 4), 256, 0, stream>>>(x, ew, cand, out);
}